// Round 6
// baseline (1254.499 us; speedup 1.0000x reference)
//
#include <hip/hip_runtime.h>
#include <hip/hip_bf16.h>

#define B_   8
#define T_   12
#define CIN  16
#define HD   96
#define COUT 8
#define CE   112
#define CD   104
#define HW   4096
#define WIMG 64

// LDS partition (shorts): tile [0,31680) | wbuf [31680,74688) | kbuf [74688,78272)
#define TILE_SH 31680
#define WBUF_SH 31680
#define KBUF_SH 74688
#define LDS_SHORTS 78272
#define LDS_BYTES (LDS_SHORTS * 2)

typedef __hip_bfloat16 bf16;
typedef __attribute__((ext_vector_type(8))) short bf16x8;   // 8 bf16 (4 VGPRs)
typedef __attribute__((ext_vector_type(16))) float f32x16;  // MFMA 32x32 C/D
typedef __attribute__((ext_vector_type(4))) int i32x4;      // 16B payload

__device__ __forceinline__ float b2f(bf16 v) { return __bfloat162float(v); }
__device__ __forceinline__ float sigmf_(float x) { return 1.0f / (1.0f + __expf(-x)); }
__device__ __forceinline__ float tanhf_(float x) { return 2.0f / (1.0f + __expf(-2.0f * x)) - 1.0f; }

__device__ __forceinline__ float ldin(const void* p, long i, int f32) {
    return f32 ? ((const float*)p)[i] : b2f(((const bf16*)p)[i]);
}
__device__ __forceinline__ short f2bs(float v) {
    __hip_bfloat16 hv = __float2bfloat16(v);
    return *reinterpret_cast<short*>(&hv);
}

// ---------------------------------------------------------------------------
// MFMA via inline asm with "+a": accumulators live in AGPRs, freeing VGPRs.
// ---------------------------------------------------------------------------
__device__ __forceinline__ void mfma_a(f32x16& acc, bf16x8 a, bf16x8 b) {
    asm("v_mfma_f32_32x32x16_bf16 %0, %1, %2, %0"
        : "+a"(acc) : "v"(a), "v"(b));
}

// ---------------------------------------------------------------------------
// 16B device-coherent (bypass) loads/stores for cross-block h exchange.
// ---------------------------------------------------------------------------
__device__ __forceinline__ i32x4 ldB16(const short* p) {
    i32x4 r;
    asm volatile("global_load_dwordx4 %0, %1, off sc0 sc1"
                 : "=v"(r) : "v"(p) : "memory");
    return r;
}
__device__ __forceinline__ void stB16(short* p, i32x4 v) {
    asm volatile("global_store_dwordx4 %0, %1, off sc0 sc1"
                 :: "v"(p), "v"(v) : "memory");
}
__device__ __forceinline__ void vm0() {
    asm volatile("s_waitcnt vmcnt(0)" ::: "memory");
}

// ---------------------------------------------------------------------------
// grouped 16B copy: TOT items; per item i, lambda gives src/dst. Batches of 8
// loads then 8 LDS writes so global latency is amortized 8-deep.
// ---------------------------------------------------------------------------
template <int TOT, typename FS, typename FD>
__device__ __forceinline__ void stage_copy(int tid, FS fsrc, FD fdst) {
    constexpr int RN = (TOT + 255) / 256;
    #pragma unroll
    for (int g0 = 0; g0 < RN; g0 += 8) {
        i32x4 tmp[8];
        #pragma unroll
        for (int r = 0; r < 8; r++) {
            int rr = g0 + r, i = tid + rr * 256;
            if (rr < RN && i < TOT) tmp[r] = *fsrc(i);
        }
        #pragma unroll
        for (int r = 0; r < 8; r++) {
            int rr = g0 + r, i = tid + rr * 256;
            if (rr < RN && i < TOT) *fdst(i) = tmp[r];
        }
    }
}

// ---------------------------------------------------------------------------
// neighbor-pair progress sync (per-block counter on its own 64B line).
// ---------------------------------------------------------------------------
__device__ __forceinline__ void wait_prog(const int* p, int need) {
    while (__hip_atomic_load(p, __ATOMIC_RELAXED, __HIP_MEMORY_SCOPE_AGENT) < need)
        __builtin_amdgcn_s_sleep(1);
}

__device__ __forceinline__ int detect_flag(const void* w) {
    const unsigned short* u = (const unsigned short*)w;
    int bad = 0;
    for (int i = 0; i < 64; i++) {
        unsigned short v = u[i];
        unsigned e = (v >> 7) & 0xFF;
        if (!(v == 0 || (e >= 90 && e <= 128))) bad++;
    }
    return (bad > 8) ? 1 : 0;
}

// ---------------------------------------------------------------------------
// ONE fused setup kernel. Block ranges:
//   0-2: biases  3: b2+flag  4: prog zero  5-25: EW  26-214: WtA  215-230: K2A
// ---------------------------------------------------------------------------
__global__ void setup_k(
    const void* eWf, const void* ebf_, const void* eWi, const void* ebi_,
    const void* eWc, const void* ebc_, const void* eWo, const void* ebo_,
    const void* dKf, const void* dbf_, const void* dKi, const void* dbi_,
    const void* dKc, const void* dbc_, const void* dWo, const void* dbo_,
    const void* oK,  const void* obv,  const void* lW,  const void* lb,
    float* __restrict__ biases, float* __restrict__ b2,
    short* __restrict__ EW, short* __restrict__ WtA, short* __restrict__ K2A,
    int* __restrict__ flag, int* __restrict__ prog)
{
    const int f = detect_flag(eWf);
    const int bid = blockIdx.x, tid = threadIdx.x;

    if (bid < 3) {                               // biases
        int idx = bid * 256 + tid;
        if (idx < 768) {
            const void* srcs[8] = {ebf_, ebi_, ebc_, ebo_, dbf_, dbi_, dbc_, dbo_};
            biases[idx] = ldin(srcs[idx / 96], idx % 96, f);
        }
        return;
    }
    if (bid == 3) {                              // b2 + flag
        if (tid < COUT) {
            float a = ldin(lb, tid, f);
            for (int cd = 0; cd < CD; cd++)
                a = fmaf(ldin(obv, cd, f), ldin(lW, cd * COUT + tid, f), a);
            b2[tid] = a;
        }
        if (tid == 32) *flag = f;
        return;
    }
    if (bid == 4) {                              // zero progress flags
        __hip_atomic_store(&prog[tid * 16], 0, __ATOMIC_RELAXED, __HIP_MEMORY_SCOPE_AGENT);
        return;
    }
    if (bid < 26) {                              // EW
        int lin = (bid - 5) * 256 + tid;
        if (lin >= 7 * 12 * 64) return;
        int lane = lin & 63;
        int rest = lin >> 6;
        int mt = rest % 12;
        int k0 = rest / 12;
        int m = mt * 32 + (lane & 31);
        int gate = m / 96, d = m % 96;
        int chb = k0 * 16 + (lane >> 5) * 8;
        const void* W = (gate == 0) ? eWf : (gate == 1) ? eWi : (gate == 2) ? eWc : eWo;
        #pragma unroll
        for (int j = 0; j < 8; j++)
            EW[(size_t)lin * 8 + j] = f2bs(ldin(W, (size_t)(chb + j) * HD + d, f));
        return;
    }
    if (bid < 215) {                             // WtA
        int lin = (bid - 26) * 256 + tid;
        if (lin >= 9 * 7 * 12 * 64) return;
        int lane = lin & 63;
        int rest = lin >> 6;
        int mt  = rest % 12;
        int k07 = rest / 12;
        int k0  = k07 % 7;
        int tap = k07 / 7;
        int m = mt * 32 + (lane & 31);
        int gate = m / 96, d = m % 96;
        int chb = k0 * 16 + (lane >> 5) * 8;
        #pragma unroll
        for (int j = 0; j < 8; j++) {
            int ch = chb + j;
            float v = 0.f;
            if (ch < 104) {
                long ki = ((long)d * CD + ch) * 9 + tap;
                if (gate == 0)      v = ldin(dKf, ki, f);
                else if (gate == 1) v = ldin(dKi, ki, f);
                else if (gate == 2) v = ldin(dKc, ki, f);
                else                v = (tap == 4) ? ldin(dWo, (long)ch * HD + d, f) : 0.f;
            }
            WtA[(size_t)lin * 8 + j] = f2bs(v);
        }
        return;
    }
    {                                            // K2A with combine inline
        int lin = (bid - 215) * 256 + tid;
        if (lin >= 9 * 7 * 64) return;
        int lane = lin & 63;
        int rest = lin >> 6;
        int k0 = rest % 7;
        int tap = rest / 7;
        int m = lane & 31;
        int kb = k0 * 16 + (lane >> 5) * 8;
        #pragma unroll 1
        for (int j = 0; j < 8; j++) {
            int c = kb + j - 8;
            float v = 0.f;
            if (m < 8 && c >= 0 && c < 96) {
                long i = (long)c * 9 + tap;
                for (int cd = 0; cd < CD; cd++)
                    v = fmaf(ldin(oK, (long)cd * (HD * 9) + i, f),
                             ldin(lW, (long)cd * COUT + m, f), v);
            }
            K2A[(size_t)lin * 8 + j] = f2bs(v);
        }
    }
}

// ---------------------------------------------------------------------------
// persistent kernel. grid 256 = 32 bands x 8 batch, block 256 = 4 waves,
// 1 block/CU. accs in AGPRs; weights staged in LDS (shared by all 4 waves --
// kills the 4x redundant A-fragment stream through L1/L2 that bounded R5).
// Encoder EW resident in LDS for all 12 steps; decoder per-tap staging.
// ---------------------------------------------------------------------------
__global__ void __launch_bounds__(256, 1) net_k(
    const void* __restrict__ xe, const void* __restrict__ xd,
    short* __restrict__ hPA, short* __restrict__ hPB,
    void* __restrict__ out,
    const short* __restrict__ EWg, const short* __restrict__ WtA,
    const short* __restrict__ K2Ag,
    const float* __restrict__ ebf, const float* __restrict__ ebi,
    const float* __restrict__ ebc, const float* __restrict__ ebo,
    const float* __restrict__ dbf, const float* __restrict__ dbi,
    const float* __restrict__ dbc, const float* __restrict__ dbo,
    const float* __restrict__ b2, const int* __restrict__ flag,
    int* __restrict__ prog)
{
    extern __shared__ short lds[];            // 156,544 B dynamic
    short* wlds = lds + WBUF_SH;              // 84 chunks x 512 shorts
    short* klds = lds + KBUF_SH;              // 7 chunks x 512 shorts
    const int f32 = *flag;
    const int tid  = threadIdx.x;
    const int b    = blockIdx.x & 7;
    const int band = blockIdx.x >> 3;         // 0..31
    const int y0   = band * 2;
    const int pix0 = y0 * 64;
    const int wave = tid >> 6, lane = tid & 63;
    const int n = lane & 31, kj = lane >> 5;
    const int px = wave * 32 + n;             // block-local pixel 0..127
    const int pg = pix0 + px;                 // global pixel
    const i32x4 z4 = {0, 0, 0, 0};

    float cre[48];
    #pragma unroll
    for (int i = 0; i < 48; i++) cre[i] = 0.f;

    // stage encoder weights ONCE (resident across all 12 encoder steps)
    stage_copy<84 * 64>(tid,
        [&](int i) { return (const i32x4*)(EWg + (size_t)i * 8); },
        [&](int i) { return (i32x4*)(wlds + (size_t)i * 8); });
    __syncthreads();

    // ================= encoder phase: h entirely in LDS recs [px][120] =====
    #pragma unroll 1
    for (int t = 0; t < T_; t++) {
        // x staging: 16 ch x 32 quads
        #pragma unroll
        for (int it = 0; it < 2; it++) {
            int i = tid + it * 256;
            int ch = i & 15, q = i >> 4;
            size_t base = ((size_t)(b * T_ + t) * CIN + ch) * HW + pix0 + q * 4;
            short v0, v1, v2, v3;
            if (f32) {
                float4 f = *(const float4*)((const float*)xe + base);
                v0 = f2bs(f.x); v1 = f2bs(f.y); v2 = f2bs(f.z); v3 = f2bs(f.w);
            } else {
                short4 sv = *(const short4*)((const short*)xe + base);
                v0 = sv.x; v1 = sv.y; v2 = sv.z; v3 = sv.w;
            }
            int sb = q * 4;
            lds[(sb + 0) * 120 + ch] = v0;
            lds[(sb + 1) * 120 + ch] = v1;
            lds[(sb + 2) * 120 + ch] = v2;
            lds[(sb + 3) * 120 + ch] = v3;
        }
        __syncthreads();

        f32x16 acc[12];
        #pragma unroll
        for (int m = 0; m < 12; m++)
            #pragma unroll
            for (int r = 0; r < 16; r++) acc[m][r] = 0.f;

        const short* rec = &lds[px * 120];
        const int k0max = (t == 0) ? 1 : 7;
        #pragma unroll 1
        for (int k0 = 0; k0 < k0max; k0++) {
            bf16x8 bB = *(const bf16x8*)(rec + k0 * 16 + kj * 8);
            #pragma unroll
            for (int mt = 0; mt < 12; mt++)
                mfma_a(acc[mt], *(const bf16x8*)(wlds + (k0 * 12 + mt) * 512 + lane * 8), bB);
        }
        __syncthreads();

        // epilogue: LSTM pointwise, c in regs, h -> own LDS rec (+16 offset)
        #pragma unroll
        for (int dt = 0; dt < 3; dt++) {
            #pragma unroll
            for (int r = 0; r < 16; r++) {
                int row = (r & 3) + 8 * (r >> 2) + 4 * kj;
                int d = dt * 32 + row;
                float fg = sigmf_(acc[dt][r]     + ebf[d]);
                float ig = sigmf_(acc[3 + dt][r] + ebi[d]);
                float gg = tanhf_(acc[6 + dt][r] + ebc[d]);
                float og = sigmf_(acc[9 + dt][r] + ebo[d]);
                int ci = dt * 16 + r;
                float cn = fmaf(cre[ci], fg, ig * gg);
                cre[ci] = cn;
                lds[px * 120 + 16 + d] = f2bs(tanhf_(cn) * og);
            }
        }
        __syncthreads();
        if (t == T_ - 1) {
            // publish final enc h to hPA (pixel-major 96-ch records), coherent
            int px2 = tid >> 1, half = tid & 1;
            short* gdst = hPA + ((size_t)b * HW + pix0 + px2) * 96 + half * 48;
            const short* lsrc = &lds[px2 * 120 + 16 + half * 48];
            #pragma unroll
            for (int s2 = 0; s2 < 6; s2++)
                stB16(gdst + s2 * 8, *(const i32x4*)(lsrc + s2 * 8));
        }
    }
    // signal: enc h published (prog = 1)
    vm0();
    __syncthreads();
    if (tid == 0)
        __hip_atomic_store(&prog[blockIdx.x * 16], 1, __ATOMIC_RELAXED, __HIP_MEMORY_SCOPE_AGENT);

    // ================= decoder phase =====
    #pragma unroll 1
    for (int tt = 0; tt <= T_; tt++) {
        short* hR  = (tt & 1) ? hPB : hPA;    // h_{tt-1}
        short* hWr = (tt & 1) ? hPA : hPB;    // h_tt

        if (tt == 0) {
            // zero pass: edge slots + ch pads (disjoint from all staging)
            #pragma unroll 1
            for (int i = tid; i < 648; i += 256) {
                int addr_sh;
                if (i < 120) {
                    int r = i / 30, rem = i % 30;
                    int s = (rem / 15) * 65;
                    addr_sh = (r * 66 + s) * 120 + (rem % 15) * 8;
                } else {
                    int z = i - 120;
                    addr_sh = (z >> 1) * 120 + 104 + (z & 1) * 8;
                }
                *(i32x4*)(&lds[addr_sh]) = z4;
            }
        }
        // x staging FIRST (no neighbor dependency -> overlaps the wait)
        if (tt < T_) {
            #pragma unroll
            for (int it = 0; it < 2; it++) {
                int i = tid + it * 256;
                int ch = i & 7, q = (i >> 3) & 15, r = i >> 7;
                int y = y0 - 1 + r;
                short v0 = 0, v1 = 0, v2 = 0, v3 = 0;
                if ((unsigned)y < 64u) {
                    size_t base = ((size_t)(b * T_ + tt) * COUT + ch) * HW + y * 64 + q * 4;
                    if (f32) {
                        float4 f = *(const float4*)((const float*)xd + base);
                        v0 = f2bs(f.x); v1 = f2bs(f.y); v2 = f2bs(f.z); v3 = f2bs(f.w);
                    } else {
                        short4 sv = *(const short4*)((const short*)xd + base);
                        v0 = sv.x; v1 = sv.y; v2 = sv.z; v3 = sv.w;
                    }
                }
                int sb = r * 66 + 1 + q * 4;
                lds[(sb + 0) * 120 + ch] = v0;
                lds[(sb + 1) * 120 + ch] = v1;
                lds[(sb + 2) * 120 + ch] = v2;
                lds[(sb + 3) * 120 + ch] = v3;
            }
        }

        // neighbor sync: need h_{tt-1} of bands band+-1 published (prog>=tt+1)
        if (tid < 2) {
            int nb = band + (tid ? 1 : -1);
            if ((unsigned)nb < 32u)
                wait_prog(prog + (((nb << 3) | b) << 4), tt + 1);
        }
        __syncthreads();

        if (tt == 0) {
            // full h staging: 4 rows x 64 recs x 12 chunks (coherent loads)
            i32x4 tmp[12]; int ss2[12], jj2[12];
            #pragma unroll
            for (int i = 0; i < 12; i++) {
                int c2 = tid + i * 256;
                int s = c2 / 12, j = c2 - s * 12;
                ss2[i] = s; jj2[i] = j;
                int y = y0 - 1 + (s >> 6);
                if ((unsigned)y < 64u)
                    tmp[i] = ldB16(hR + ((size_t)b * HW + (size_t)y * 64 + (s & 63)) * 96 + j * 8);
                else tmp[i] = z4;
            }
            vm0();
            #pragma unroll
            for (int i = 0; i < 12; i++) {
                int s = ss2[i];
                *(i32x4*)(&lds[((s >> 6) * 66 + 1 + (s & 63)) * 120 + 8 + jj2[i] * 8]) = tmp[i];
            }
        } else {
            // halo staging only: rows y0-1 (slot-row 0) and y0+2 (slot-row 3)
            i32x4 tmp[6]; int ss2[6], jj2[6];
            #pragma unroll
            for (int i = 0; i < 6; i++) {
                int c2 = tid + i * 256;           // 0..1535
                int s = c2 / 12, j = c2 - s * 12; // s 0..127
                int hi = s >> 6;                  // 0 top, 1 bottom
                int y = hi ? (y0 + 2) : (y0 - 1);
                ss2[i] = hi * 3 * 66 + 1 + (s & 63);
                jj2[i] = j;
                if ((unsigned)y < 64u)
                    tmp[i] = ldB16(hR + ((size_t)b * HW + (size_t)y * 64 + (s & 63)) * 96 + j * 8);
                else tmp[i] = z4;
            }
            vm0();
            #pragma unroll
            for (int i = 0; i < 6; i++)
                *(i32x4*)(&lds[ss2[i] * 120 + 8 + jj2[i] * 8]) = tmp[i];
        }
        __syncthreads();

        const int rw = 1 + (wave >> 1);
        const int x0 = (wave & 1) * 32;
        const int ldA = (tt < T_) ? 1 : 0;

        f32x16 aF[9], aO[3], aOut;
        #pragma unroll
        for (int m = 0; m < 9; m++)
            #pragma unroll
            for (int r = 0; r < 16; r++) aF[m][r] = 0.f;
        #pragma unroll
        for (int m = 0; m < 3; m++)
            #pragma unroll
            for (int r = 0; r < 16; r++) aO[m][r] = 0.f;
        #pragma unroll
        for (int r = 0; r < 16; r++) aOut[r] = 0.f;

        // main tap loop: stage tap weights -> barrier -> MFMA -> barrier
        #pragma unroll 1
        for (int tap = 0; tap < 9; tap++) {
            // ---- stage this tap's weights into LDS (all waves cooperate)
            if (ldA) {
                if (tap == 4) {
                    stage_copy<84 * 64>(tid,
                        [&](int i) { int c = i >> 6, l = i & 63;
                            return (const i32x4*)(WtA + (((size_t)tap * 84 + c) * 64 + l) * 8); },
                        [&](int i) { int c = i >> 6, l = i & 63;
                            return (i32x4*)(wlds + c * 512 + l * 8); });
                } else {
                    stage_copy<63 * 64>(tid,
                        [&](int i) { int c = i >> 6, l = i & 63, k0 = c / 9, mt = c - k0 * 9;
                            return (const i32x4*)(WtA + (((size_t)tap * 84 + k0 * 12 + mt) * 64 + l) * 8); },
                        [&](int i) { int c = i >> 6, l = i & 63, k0 = c / 9, mt = c - k0 * 9;
                            return (i32x4*)(wlds + (k0 * 12 + mt) * 512 + l * 8); });
                }
            }
            stage_copy<7 * 64>(tid,
                [&](int i) { int c = i >> 6, l = i & 63;
                    return (const i32x4*)(K2Ag + (((size_t)tap * 7 + c) * 64 + l) * 8); },
                [&](int i) { int c = i >> 6, l = i & 63;
                    return (i32x4*)(klds + c * 512 + l * 8); });
            __syncthreads();

            // ---- MFMA from LDS
            int dy = tap / 3 - 1, dx = tap - (tap / 3) * 3 - 1;
            const short* rec = &lds[((rw + dy) * 66 + 1 + x0 + n + dx) * 120];
            #pragma unroll
            for (int k0 = 0; k0 < 7; k0++) {
                bf16x8 bB = *(const bf16x8*)(rec + k0 * 16 + kj * 8);
                if (tt < T_) {
                    #pragma unroll
                    for (int mt = 0; mt < 9; mt++)
                        mfma_a(aF[mt], *(const bf16x8*)(wlds + (k0 * 12 + mt) * 512 + lane * 8), bB);
                    if (tap == 4) {
                        #pragma unroll
                        for (int q = 0; q < 3; q++)
                            mfma_a(aO[q], *(const bf16x8*)(wlds + (k0 * 12 + 9 + q) * 512 + lane * 8), bB);
                    }
                }
                if (tt > 0)
                    mfma_a(aOut, *(const bf16x8*)(klds + k0 * 512 + lane * 8), bB);
            }
            __syncthreads();
        }

        // fused out store for step tt-1 (C rows 0..7 = out channels)
        if (tt > 0) {
            #pragma unroll
            for (int r = 0; r < 4; r++) {
                int o = r + 4 * kj;
                float v = aOut[r] + b2[o];
                size_t oadr = ((size_t)(b * T_ + (tt - 1)) * COUT + o) * HW + pg;
                if (f32) ((float*)out)[oadr] = v;
                else     ((bf16*)out)[oadr] = __float2bfloat16(v);
            }
        }

        if (tt < T_) {
            // epilogue: LSTM pointwise, c in regs, h -> own staged recs
            #pragma unroll
            for (int dt = 0; dt < 3; dt++) {
                #pragma unroll
                for (int r = 0; r < 16; r++) {
                    int row = (r & 3) + 8 * (r >> 2) + 4 * kj;
                    int d = dt * 32 + row;
                    float fg = sigmf_(aF[dt][r]     + dbf[d]);
                    float ig = sigmf_(aF[3 + dt][r] + dbi[d]);
                    float gg = tanhf_(aF[6 + dt][r] + dbc[d]);
                    float og = sigmf_(aO[dt][r]     + dbo[d]);
                    int ci = dt * 16 + r;
                    float cn = fmaf(cre[ci], fg, ig * gg);
                    cre[ci] = cn;
                    float hv = tanhf_(cn) * og;
                    lds[((1 + (px >> 6)) * 66 + 1 + (px & 63)) * 120 + 8 + d] = f2bs(hv);
                }
            }
            __syncthreads();
            // publish own 2 rows to hWr (pixel-major records), coherent
            int px2 = tid >> 1, half = tid & 1;
            short* gdst = hWr + ((size_t)b * HW + pix0 + px2) * 96 + half * 48;
            const short* lsrc = &lds[((1 + (px2 >> 6)) * 66 + 1 + (px2 & 63)) * 120 + 8 + half * 48];
            #pragma unroll
            for (int s2 = 0; s2 < 6; s2++)
                stB16(gdst + s2 * 8, *(const i32x4*)(lsrc + s2 * 8));
            // signal: h_tt published (prog = tt+2)
            vm0();
            __syncthreads();
            if (tid == 0)
                __hip_atomic_store(&prog[blockIdx.x * 16], tt + 2,
                                   __ATOMIC_RELAXED, __HIP_MEMORY_SCOPE_AGENT);
        }
        // no signal after the final out-only pass (tt == T_)
    }
}

// ---------------------------------------------------------------------------
extern "C" void kernel_launch(void* const* d_in, const int* in_sizes, int n_in,
                              void* d_out, int out_size, void* d_ws, size_t ws_size,
                              hipStream_t stream)
{
    const void* enc_in = d_in[0];
    const void* dec_in = d_in[1];
    const void* eWf = d_in[2];  const void* ebf_ = d_in[3];
    const void* eWi = d_in[4];  const void* ebi_ = d_in[5];
    const void* eWc = d_in[6];  const void* ebc_ = d_in[7];
    const void* eWo = d_in[8];  const void* ebo_ = d_in[9];
    const void* dKf = d_in[10]; const void* dbf_ = d_in[11];
    const void* dKi = d_in[12]; const void* dbi_ = d_in[13];
    const void* dKc = d_in[14]; const void* dbc_ = d_in[15];
    const void* dWo = d_in[16]; const void* dbo_ = d_in[17];
    const void* oK  = d_in[18]; const void* obv = d_in[19];
    const void* lW  = d_in[20]; const void* lb  = d_in[21];

    int* flag = (int*)d_ws;
    int* prog = (int*)d_ws + 16;             // 256 slots x 16 ints (64B stride)
    float* ws = (float*)d_ws + 16 + 4096;

    const int S = B_ * HD * HW;              // 3,145,728 state elems
    short* hPA = (short*)ws;                 // S shorts (pixel-major h)
    short* hPB = (short*)(ws + S / 2);       // S shorts
    float* biases = ws + S;                  // 8 x 96 fp32
    float* b2   = biases + 768;              // 16
    short* WtA  = (short*)(b2 + 16);                  // 387,072 shorts
    short* EW   = (short*)(b2 + 16 + 193536);         // 43,008 shorts
    short* K2A  = (short*)(b2 + 16 + 193536 + 21504); // 32,256 shorts

    hipFuncSetAttribute(reinterpret_cast<const void*>(net_k),
                        hipFuncAttributeMaxDynamicSharedMemorySize, LDS_BYTES);

    setup_k<<<dim3(231), dim3(256), 0, stream>>>(
        eWf, ebf_, eWi, ebi_, eWc, ebc_, eWo, ebo_,
        dKf, dbf_, dKi, dbi_, dKc, dbc_, dWo, dbo_,
        oK, obv, lW, lb,
        biases, b2, EW, WtA, K2A, flag, prog);

    net_k<<<dim3(256), dim3(256), LDS_BYTES, stream>>>(
        enc_in, dec_in, hPA, hPB, d_out,
        EW, WtA, K2A,
        biases + 0, biases + 96, biases + 192, biases + 288,
        biases + 384, biases + 480, biases + 576, biases + 672,
        b2, flag, prog);
}

// Round 9
// 1048.787 us; speedup vs baseline: 1.1961x; 1.1961x over previous
//
#include <hip/hip_runtime.h>
#include <hip/hip_bf16.h>

#define B_   8
#define T_   12
#define CIN  16
#define HD   96
#define COUT 8
#define CE   112
#define CD   104
#define HW   4096
#define WIMG 64

// LDS partition (shorts):
//   tile [0, 31680)            4 x 66 x 120 halo tile
//   WA   [31680, 51648)        unit buffer A: 3 k0-slots x 13 chunks x 512
//   WB   [51648, 71616)        unit buffer B
//   encoder reuses [31680, 74688) for the 84-chunk resident EW
#define TILE_SH 31680
#define WA_SH 31680
#define UBUF_SH (3 * 13 * 512)
#define WB_SH (WA_SH + UBUF_SH)
#define LDS_SHORTS 74688
#define LDS_BYTES (LDS_SHORTS * 2)

typedef __hip_bfloat16 bf16;
typedef __attribute__((ext_vector_type(8))) short bf16x8;   // 8 bf16 (4 VGPRs)
typedef __attribute__((ext_vector_type(16))) float f32x16;  // MFMA 32x32 C/D
typedef __attribute__((ext_vector_type(4))) int i32x4;      // 16B payload

__device__ __forceinline__ float b2f(bf16 v) { return __bfloat162float(v); }
__device__ __forceinline__ float sigmf_(float x) { return 1.0f / (1.0f + __expf(-x)); }
__device__ __forceinline__ float tanhf_(float x) { return 2.0f / (1.0f + __expf(-2.0f * x)) - 1.0f; }

__device__ __forceinline__ float ldin(const void* p, long i, int f32) {
    return f32 ? ((const float*)p)[i] : b2f(((const bf16*)p)[i]);
}
__device__ __forceinline__ short f2bs(float v) {
    __hip_bfloat16 hv = __float2bfloat16(v);
    return *reinterpret_cast<short*>(&hv);
}

// ---------------------------------------------------------------------------
// MFMA via inline asm with "+a": accumulators in AGPRs (frees VGPRs).
// ---------------------------------------------------------------------------
__device__ __forceinline__ void mfma_a(f32x16& acc, bf16x8 a, bf16x8 b) {
    asm("v_mfma_f32_32x32x16_bf16 %0, %1, %2, %0"
        : "+a"(acc) : "v"(a), "v"(b));
}

// ---------------------------------------------------------------------------
// async global->LDS 16B DMA: no VGPR round-trip (no spill pressure), compiler
// tracks vmcnt. Dest = wave-uniform LDS base + lane*16. Src is per-lane.
// ---------------------------------------------------------------------------
#if defined(__has_builtin)
#if __has_builtin(__builtin_amdgcn_global_load_lds)
#define HAVE_GLLDS 1
#endif
#endif

__device__ __forceinline__ void gl_lds16(const short* g, short* l, int lane) {
#ifdef HAVE_GLLDS
    __builtin_amdgcn_global_load_lds(
        (const __attribute__((address_space(1))) void*)g,
        (__attribute__((address_space(3))) void*)l, 16, 0, 0);
#else
    *(i32x4*)(l + lane * 8) = *(const i32x4*)g;   // fallback: reg round-trip
#endif
}

// ---------------------------------------------------------------------------
// 16B device-coherent (bypass) loads/stores for cross-block h exchange.
// ---------------------------------------------------------------------------
__device__ __forceinline__ i32x4 ldB16(const short* p) {
    i32x4 r;
    asm volatile("global_load_dwordx4 %0, %1, off sc0 sc1"
                 : "=v"(r) : "v"(p) : "memory");
    return r;
}
__device__ __forceinline__ void stB16(short* p, i32x4 v) {
    asm volatile("global_store_dwordx4 %0, %1, off sc0 sc1"
                 :: "v"(p), "v"(v) : "memory");
}
__device__ __forceinline__ void vm0() {
    asm volatile("s_waitcnt vmcnt(0)" ::: "memory");
}

// ---------------------------------------------------------------------------
// neighbor-pair progress sync (per-block counter on its own 64B line).
// ---------------------------------------------------------------------------
__device__ __forceinline__ void wait_prog(const int* p, int need) {
    while (__hip_atomic_load(p, __ATOMIC_RELAXED, __HIP_MEMORY_SCOPE_AGENT) < need)
        __builtin_amdgcn_s_sleep(1);
}

__device__ __forceinline__ int detect_flag(const void* w) {
    const unsigned short* u = (const unsigned short*)w;
    int bad = 0;
    for (int i = 0; i < 64; i++) {
        unsigned short v = u[i];
        unsigned e = (v >> 7) & 0xFF;
        if (!(v == 0 || (e >= 90 && e <= 128))) bad++;
    }
    return (bad > 8) ? 1 : 0;
}

// ---------------------------------------------------------------------------
// ONE fused setup kernel. Block ranges:
//   0-2: biases  3: b2+flag  4: prog zero  5-25: EW  26-214: WtA  215-230: K2A
// ---------------------------------------------------------------------------
__global__ void setup_k(
    const void* eWf, const void* ebf_, const void* eWi, const void* ebi_,
    const void* eWc, const void* ebc_, const void* eWo, const void* ebo_,
    const void* dKf, const void* dbf_, const void* dKi, const void* dbi_,
    const void* dKc, const void* dbc_, const void* dWo, const void* dbo_,
    const void* oK,  const void* obv,  const void* lW,  const void* lb,
    float* __restrict__ biases, float* __restrict__ b2,
    short* __restrict__ EW, short* __restrict__ WtA, short* __restrict__ K2A,
    int* __restrict__ flag, int* __restrict__ prog)
{
    const int f = detect_flag(eWf);
    const int bid = blockIdx.x, tid = threadIdx.x;

    if (bid < 3) {                               // biases
        int idx = bid * 256 + tid;
        if (idx < 768) {
            const void* srcs[8] = {ebf_, ebi_, ebc_, ebo_, dbf_, dbi_, dbc_, dbo_};
            biases[idx] = ldin(srcs[idx / 96], idx % 96, f);
        }
        return;
    }
    if (bid == 3) {                              // b2 + flag
        if (tid < COUT) {
            float a = ldin(lb, tid, f);
            for (int cd = 0; cd < CD; cd++)
                a = fmaf(ldin(obv, cd, f), ldin(lW, cd * COUT + tid, f), a);
            b2[tid] = a;
        }
        if (tid == 32) *flag = f;
        return;
    }
    if (bid == 4) {                              // zero progress flags
        __hip_atomic_store(&prog[tid * 16], 0, __ATOMIC_RELAXED, __HIP_MEMORY_SCOPE_AGENT);
        return;
    }
    if (bid < 26) {                              // EW
        int lin = (bid - 5) * 256 + tid;
        if (lin >= 7 * 12 * 64) return;
        int lane = lin & 63;
        int rest = lin >> 6;
        int mt = rest % 12;
        int k0 = rest / 12;
        int m = mt * 32 + (lane & 31);
        int gate = m / 96, d = m % 96;
        int chb = k0 * 16 + (lane >> 5) * 8;
        const void* W = (gate == 0) ? eWf : (gate == 1) ? eWi : (gate == 2) ? eWc : eWo;
        #pragma unroll
        for (int j = 0; j < 8; j++)
            EW[(size_t)lin * 8 + j] = f2bs(ldin(W, (size_t)(chb + j) * HD + d, f));
        return;
    }
    if (bid < 215) {                             // WtA
        int lin = (bid - 26) * 256 + tid;
        if (lin >= 9 * 7 * 12 * 64) return;
        int lane = lin & 63;
        int rest = lin >> 6;
        int mt  = rest % 12;
        int k07 = rest / 12;
        int k0  = k07 % 7;
        int tap = k07 / 7;
        int m = mt * 32 + (lane & 31);
        int gate = m / 96, d = m % 96;
        int chb = k0 * 16 + (lane >> 5) * 8;
        #pragma unroll
        for (int j = 0; j < 8; j++) {
            int ch = chb + j;
            float v = 0.f;
            if (ch < 104) {
                long ki = ((long)d * CD + ch) * 9 + tap;
                if (gate == 0)      v = ldin(dKf, ki, f);
                else if (gate == 1) v = ldin(dKi, ki, f);
                else if (gate == 2) v = ldin(dKc, ki, f);
                else                v = (tap == 4) ? ldin(dWo, (long)ch * HD + d, f) : 0.f;
            }
            WtA[(size_t)lin * 8 + j] = f2bs(v);
        }
        return;
    }
    {                                            // K2A with combine inline
        int lin = (bid - 215) * 256 + tid;
        if (lin >= 9 * 7 * 64) return;
        int lane = lin & 63;
        int rest = lin >> 6;
        int k0 = rest % 7;
        int tap = rest / 7;
        int m = lane & 31;
        int kb = k0 * 16 + (lane >> 5) * 8;
        #pragma unroll 1
        for (int j = 0; j < 8; j++) {
            int c = kb + j - 8;
            float v = 0.f;
            if (m < 8 && c >= 0 && c < 96) {
                long i = (long)c * 9 + tap;
                for (int cd = 0; cd < CD; cd++)
                    v = fmaf(ldin(oK, (long)cd * (HD * 9) + i, f),
                             ldin(lW, (long)cd * COUT + m, f), v);
            }
            K2A[(size_t)lin * 8 + j] = f2bs(v);
        }
    }
}

// ---------------------------------------------------------------------------
// persistent kernel. grid 256 = 32 bands x 8 batch, block 256 = 4 waves,
// 1 block/CU. accs in AGPRs; decoder weights staged into LDS via async
// global_load_lds DMA (zero VGPR cost -> no spills), double-buffered at
// sub-tap granularity: 27 units/step, stage(u+1) issued before MFMA(u).
// All 4 waves share the staged copy (kills the 4x redundant A-stream).
// ---------------------------------------------------------------------------
__global__ void __launch_bounds__(256, 1) net_k(
    const void* __restrict__ xe, const void* __restrict__ xd,
    short* __restrict__ hPA, short* __restrict__ hPB,
    void* __restrict__ out,
    const short* __restrict__ EWg, const short* __restrict__ WtA,
    const short* __restrict__ K2Ag,
    const float* __restrict__ ebf, const float* __restrict__ ebi,
    const float* __restrict__ ebc, const float* __restrict__ ebo,
    const float* __restrict__ dbf, const float* __restrict__ dbi,
    const float* __restrict__ dbc, const float* __restrict__ dbo,
    const float* __restrict__ b2, const int* __restrict__ flag,
    int* __restrict__ prog)
{
    extern __shared__ short lds[];            // 149,376 B dynamic
    const int f32 = *flag;
    const int tid  = threadIdx.x;
    const int b    = blockIdx.x & 7;
    const int band = blockIdx.x >> 3;         // 0..31
    const int y0   = band * 2;
    const int pix0 = y0 * 64;
    const int wave = tid >> 6, lane = tid & 63;
    const int n = lane & 31, kj = lane >> 5;
    const int px = wave * 32 + n;             // block-local pixel 0..127
    const int pg = pix0 + px;                 // global pixel
    const i32x4 z4 = {0, 0, 0, 0};

    float cre[48];
    #pragma unroll
    for (int i = 0; i < 48; i++) cre[i] = 0.f;

    // stage encoder weights ONCE via async DMA (resident all 12 enc steps)
    #pragma unroll 1
    for (int c = wave; c < 84; c += 4)
        gl_lds16(EWg + (size_t)c * 512 + lane * 8, lds + TILE_SH + c * 512, lane);
    vm0();
    __syncthreads();

    // ================= encoder phase: h entirely in LDS recs [px][120] =====
    #pragma unroll 1
    for (int t = 0; t < T_; t++) {
        // x staging: 16 ch x 32 quads
        #pragma unroll
        for (int it = 0; it < 2; it++) {
            int i = tid + it * 256;
            int ch = i & 15, q = i >> 4;
            size_t base = ((size_t)(b * T_ + t) * CIN + ch) * HW + pix0 + q * 4;
            short v0, v1, v2, v3;
            if (f32) {
                float4 f = *(const float4*)((const float*)xe + base);
                v0 = f2bs(f.x); v1 = f2bs(f.y); v2 = f2bs(f.z); v3 = f2bs(f.w);
            } else {
                short4 sv = *(const short4*)((const short*)xe + base);
                v0 = sv.x; v1 = sv.y; v2 = sv.z; v3 = sv.w;
            }
            int sb = q * 4;
            lds[(sb + 0) * 120 + ch] = v0;
            lds[(sb + 1) * 120 + ch] = v1;
            lds[(sb + 2) * 120 + ch] = v2;
            lds[(sb + 3) * 120 + ch] = v3;
        }
        __syncthreads();

        f32x16 acc[12];
        #pragma unroll
        for (int m = 0; m < 12; m++)
            #pragma unroll
            for (int r = 0; r < 16; r++) acc[m][r] = 0.f;

        const short* rec = &lds[px * 120];
        const int k0max = (t == 0) ? 1 : 7;
        #pragma unroll 1
        for (int k0 = 0; k0 < k0max; k0++) {
            bf16x8 bB = *(const bf16x8*)(rec + k0 * 16 + kj * 8);
            #pragma unroll
            for (int mt = 0; mt < 12; mt++)
                mfma_a(acc[mt], *(const bf16x8*)(lds + TILE_SH + (k0 * 12 + mt) * 512 + lane * 8), bB);
        }
        __syncthreads();

        // epilogue: LSTM pointwise, c in regs, h -> own LDS rec (+16 offset)
        #pragma unroll
        for (int dt = 0; dt < 3; dt++) {
            #pragma unroll
            for (int r = 0; r < 16; r++) {
                int row = (r & 3) + 8 * (r >> 2) + 4 * kj;
                int d = dt * 32 + row;
                float fg = sigmf_(acc[dt][r]     + ebf[d]);
                float ig = sigmf_(acc[3 + dt][r] + ebi[d]);
                float gg = tanhf_(acc[6 + dt][r] + ebc[d]);
                float og = sigmf_(acc[9 + dt][r] + ebo[d]);
                int ci = dt * 16 + r;
                float cn = fmaf(cre[ci], fg, ig * gg);
                cre[ci] = cn;
                lds[px * 120 + 16 + d] = f2bs(tanhf_(cn) * og);
            }
        }
        __syncthreads();
        if (t == T_ - 1) {
            // publish final enc h to hPA (pixel-major 96-ch records), coherent
            int px2 = tid >> 1, half = tid & 1;
            short* gdst = hPA + ((size_t)b * HW + pix0 + px2) * 96 + half * 48;
            const short* lsrc = &lds[px2 * 120 + 16 + half * 48];
            #pragma unroll
            for (int s2 = 0; s2 < 6; s2++)
                stB16(gdst + s2 * 8, *(const i32x4*)(lsrc + s2 * 8));
        }
    }
    // signal: enc h published (prog = 1)
    vm0();
    __syncthreads();
    if (tid == 0)
        __hip_atomic_store(&prog[blockIdx.x * 16], 1, __ATOMIC_RELAXED, __HIP_MEMORY_SCOPE_AGENT);

    // ================= decoder phase =====
    #pragma unroll 1
    for (int tt = 0; tt <= T_; tt++) {
        short* hR  = (tt & 1) ? hPB : hPA;    // h_{tt-1}
        short* hWr = (tt & 1) ? hPA : hPB;    // h_tt

        if (tt == 0) {
            // zero pass: edge slots + ch pads (disjoint from all staging)
            #pragma unroll 1
            for (int i = tid; i < 648; i += 256) {
                int addr_sh;
                if (i < 120) {
                    int r = i / 30, rem = i % 30;
                    int s = (rem / 15) * 65;
                    addr_sh = (r * 66 + s) * 120 + (rem % 15) * 8;
                } else {
                    int z = i - 120;
                    addr_sh = (z >> 1) * 120 + 104 + (z & 1) * 8;
                }
                *(i32x4*)(&lds[addr_sh]) = z4;
            }
        }
        // x staging FIRST (no neighbor dependency -> overlaps the wait)
        if (tt < T_) {
            #pragma unroll
            for (int it = 0; it < 2; it++) {
                int i = tid + it * 256;
                int ch = i & 7, q = (i >> 3) & 15, r = i >> 7;
                int y = y0 - 1 + r;
                short v0 = 0, v1 = 0, v2 = 0, v3 = 0;
                if ((unsigned)y < 64u) {
                    size_t base = ((size_t)(b * T_ + tt) * COUT + ch) * HW + y * 64 + q * 4;
                    if (f32) {
                        float4 f = *(const float4*)((const float*)xd + base);
                        v0 = f2bs(f.x); v1 = f2bs(f.y); v2 = f2bs(f.z); v3 = f2bs(f.w);
                    } else {
                        short4 sv = *(const short4*)((const short*)xd + base);
                        v0 = sv.x; v1 = sv.y; v2 = sv.z; v3 = sv.w;
                    }
                }
                int sb = r * 66 + 1 + q * 4;
                lds[(sb + 0) * 120 + ch] = v0;
                lds[(sb + 1) * 120 + ch] = v1;
                lds[(sb + 2) * 120 + ch] = v2;
                lds[(sb + 3) * 120 + ch] = v3;
            }
        }

        // ------- unit pipeline machinery (27 units = 9 taps x 3 k0-groups)
        const int rw = 1 + (wave >> 1);
        const int x0 = (wave & 1) * 32;

        f32x16 aF[9], aO[3], aOut;
        #pragma unroll
        for (int m = 0; m < 9; m++)
            #pragma unroll
            for (int r = 0; r < 16; r++) aF[m][r] = 0.f;
        #pragma unroll
        for (int m = 0; m < 3; m++)
            #pragma unroll
            for (int r = 0; r < 16; r++) aO[m][r] = 0.f;
        #pragma unroll
        for (int r = 0; r < 16; r++) aOut[r] = 0.f;

        auto stage_unit = [&](int u) {
            int tap = u / 3, kg = u - tap * 3;
            int base = (u & 1) ? WB_SH : WA_SH;
            int nk = (kg == 0) ? 3 : 2;
            int ks = (kg == 0) ? 0 : (kg == 1 ? 3 : 5);
            int nmt = (tap == 4) ? 12 : 9;
            #pragma unroll 1
            for (int kk = 0; kk < nk; kk++) {
                int k0 = ks + kk;
                const short* gsrc = WtA + ((size_t)(tap * 7 + k0) * 12 * 64 + lane) * 8;
                short* ldst = lds + base + kk * 13 * 512;
                if (tt < T_) {
                    #pragma unroll 1
                    for (int mt = wave; mt < nmt; mt += 4)
                        gl_lds16(gsrc + (size_t)mt * 512, ldst + mt * 512, lane);
                }
                if (tt > 0 && wave == 3)
                    gl_lds16(K2Ag + ((size_t)(tap * 7 + k0) * 64 + lane) * 8,
                             ldst + 12 * 512, lane);
            }
        };
        auto mfma_unit = [&](int u) {
            int tap = u / 3, kg = u - tap * 3;
            int base = (u & 1) ? WB_SH : WA_SH;
            int nk = (kg == 0) ? 3 : 2;
            int ks = (kg == 0) ? 0 : (kg == 1 ? 3 : 5);
            int dy = tap / 3 - 1, dx = tap - (tap / 3) * 3 - 1;
            const short* rec = &lds[((rw + dy) * 66 + 1 + x0 + n + dx) * 120];
            #pragma unroll 1
            for (int kk = 0; kk < nk; kk++) {
                int k0 = ks + kk;
                bf16x8 bB = *(const bf16x8*)(rec + k0 * 16 + kj * 8);
                const short* sb = lds + base + kk * 13 * 512 + lane * 8;
                if (tt < T_) {
                    #pragma unroll
                    for (int mt = 0; mt < 9; mt++)
                        mfma_a(aF[mt], *(const bf16x8*)(sb + mt * 512), bB);
                    if (tap == 4) {
                        #pragma unroll
                        for (int q = 0; q < 3; q++)
                            mfma_a(aO[q], *(const bf16x8*)(sb + (9 + q) * 512), bB);
                    }
                }
                if (tt > 0)
                    mfma_a(aOut, *(const bf16x8*)(sb + 12 * 512), bB);
            }
        };

        // issue unit 0 BEFORE the neighbor wait (hides sync + load latency)
        stage_unit(0);

        // neighbor sync: need h_{tt-1} of bands band+-1 published (prog>=tt+1)
        if (tid < 2) {
            int nb = band + (tid ? 1 : -1);
            if ((unsigned)nb < 32u)
                wait_prog(prog + (((nb << 3) | b) << 4), tt + 1);
        }
        __syncthreads();

        if (tt == 0) {
            // full h staging: 4 rows x 64 recs x 12 chunks (coherent loads)
            i32x4 tmp[12]; int ss2[12], jj2[12];
            #pragma unroll
            for (int i = 0; i < 12; i++) {
                int c2 = tid + i * 256;
                int s = c2 / 12, j = c2 - s * 12;
                ss2[i] = s; jj2[i] = j;
                int y = y0 - 1 + (s >> 6);
                if ((unsigned)y < 64u)
                    tmp[i] = ldB16(hR + ((size_t)b * HW + (size_t)y * 64 + (s & 63)) * 96 + j * 8);
                else tmp[i] = z4;
            }
            vm0();   // drains halo loads AND unit-0 DMA
            #pragma unroll
            for (int i = 0; i < 12; i++) {
                int s = ss2[i];
                *(i32x4*)(&lds[((s >> 6) * 66 + 1 + (s & 63)) * 120 + 8 + jj2[i] * 8]) = tmp[i];
            }
        } else {
            // halo staging only: rows y0-1 (slot-row 0) and y0+2 (slot-row 3)
            i32x4 tmp[6]; int ss2[6], jj2[6];
            #pragma unroll
            for (int i = 0; i < 6; i++) {
                int c2 = tid + i * 256;           // 0..1535
                int s = c2 / 12, j = c2 - s * 12; // s 0..127
                int hi = s >> 6;                  // 0 top, 1 bottom
                int y = hi ? (y0 + 2) : (y0 - 1);
                ss2[i] = hi * 3 * 66 + 1 + (s & 63);
                jj2[i] = j;
                if ((unsigned)y < 64u)
                    tmp[i] = ldB16(hR + ((size_t)b * HW + (size_t)y * 64 + (s & 63)) * 96 + j * 8);
                else tmp[i] = z4;
            }
            vm0();   // drains halo loads AND unit-0 DMA
            #pragma unroll
            for (int i = 0; i < 6; i++)
                *(i32x4*)(&lds[ss2[i] * 120 + 8 + jj2[i] * 8]) = tmp[i];
        }
        __syncthreads();

        // ------- 27-unit double-buffered pipeline
        #pragma unroll 1
        for (int u = 0; u < 27; u++) {
            if (u < 26) stage_unit(u + 1);    // async DMA into other buffer
            mfma_unit(u);                      // compute from current buffer
            vm0();                             // stage(u+1) landed
            __syncthreads();                   // all waves done reading buf(u)
        }

        // fused out store for step tt-1 (C rows 0..7 = out channels)
        if (tt > 0) {
            #pragma unroll
            for (int r = 0; r < 4; r++) {
                int o = r + 4 * kj;
                float v = aOut[r] + b2[o];
                size_t oadr = ((size_t)(b * T_ + (tt - 1)) * COUT + o) * HW + pg;
                if (f32) ((float*)out)[oadr] = v;
                else     ((bf16*)out)[oadr] = __float2bfloat16(v);
            }
        }

        if (tt < T_) {
            // epilogue: LSTM pointwise, c in regs, h -> own staged recs
            #pragma unroll
            for (int dt = 0; dt < 3; dt++) {
                #pragma unroll
                for (int r = 0; r < 16; r++) {
                    int row = (r & 3) + 8 * (r >> 2) + 4 * kj;
                    int d = dt * 32 + row;
                    float fg = sigmf_(aF[dt][r]     + dbf[d]);
                    float ig = sigmf_(aF[3 + dt][r] + dbi[d]);
                    float gg = tanhf_(aF[6 + dt][r] + dbc[d]);
                    float og = sigmf_(aO[dt][r]     + dbo[d]);
                    int ci = dt * 16 + r;
                    float cn = fmaf(cre[ci], fg, ig * gg);
                    cre[ci] = cn;
                    float hv = tanhf_(cn) * og;
                    lds[((1 + (px >> 6)) * 66 + 1 + (px & 63)) * 120 + 8 + d] = f2bs(hv);
                }
            }
            __syncthreads();
            // publish own 2 rows to hWr (pixel-major records), coherent
            int px2 = tid >> 1, half = tid & 1;
            short* gdst = hWr + ((size_t)b * HW + pix0 + px2) * 96 + half * 48;
            const short* lsrc = &lds[((1 + (px2 >> 6)) * 66 + 1 + (px2 & 63)) * 120 + 8 + half * 48];
            #pragma unroll
            for (int s2 = 0; s2 < 6; s2++)
                stB16(gdst + s2 * 8, *(const i32x4*)(lsrc + s2 * 8));
            // signal: h_tt published (prog = tt+2)
            vm0();
            __syncthreads();
            if (tid == 0)
                __hip_atomic_store(&prog[blockIdx.x * 16], tt + 2,
                                   __ATOMIC_RELAXED, __HIP_MEMORY_SCOPE_AGENT);
        }
        // no signal after the final out-only pass (tt == T_)
    }
}

// ---------------------------------------------------------------------------
extern "C" void kernel_launch(void* const* d_in, const int* in_sizes, int n_in,
                              void* d_out, int out_size, void* d_ws, size_t ws_size,
                              hipStream_t stream)
{
    const void* enc_in = d_in[0];
    const void* dec_in = d_in[1];
    const void* eWf = d_in[2];  const void* ebf_ = d_in[3];
    const void* eWi = d_in[4];  const void* ebi_ = d_in[5];
    const void* eWc = d_in[6];  const void* ebc_ = d_in[7];
    const void* eWo = d_in[8];  const void* ebo_ = d_in[9];
    const void* dKf = d_in[10]; const void* dbf_ = d_in[11];
    const void* dKi = d_in[12]; const void* dbi_ = d_in[13];
    const void* dKc = d_in[14]; const void* dbc_ = d_in[15];
    const void* dWo = d_in[16]; const void* dbo_ = d_in[17];
    const void* oK  = d_in[18]; const void* obv = d_in[19];
    const void* lW  = d_in[20]; const void* lb  = d_in[21];

    int* flag = (int*)d_ws;
    int* prog = (int*)d_ws + 16;             // 256 slots x 16 ints (64B stride)
    float* ws = (float*)d_ws + 16 + 4096;

    const int S = B_ * HD * HW;              // 3,145,728 state elems
    short* hPA = (short*)ws;                 // S shorts (pixel-major h)
    short* hPB = (short*)(ws + S / 2);       // S shorts
    float* biases = ws + S;                  // 8 x 96 fp32
    float* b2   = biases + 768;              // 16
    short* WtA  = (short*)(b2 + 16);                  // 387,072 shorts
    short* EW   = (short*)(b2 + 16 + 193536);         // 43,008 shorts
    short* K2A  = (short*)(b2 + 16 + 193536 + 21504); // 32,256 shorts

    hipFuncSetAttribute(reinterpret_cast<const void*>(net_k),
                        hipFuncAttributeMaxDynamicSharedMemorySize, LDS_BYTES);

    setup_k<<<dim3(231), dim3(256), 0, stream>>>(
        eWf, ebf_, eWi, ebi_, eWc, ebc_, eWo, ebo_,
        dKf, dbf_, dKi, dbi_, dKc, dbc_, dWo, dbo_,
        oK, obv, lW, lb,
        biases, b2, EW, WtA, K2A, flag, prog);

    net_k<<<dim3(256), dim3(256), LDS_BYTES, stream>>>(
        enc_in, dec_in, hPA, hPB, d_out,
        EW, WtA, K2A,
        biases + 0, biases + 96, biases + 192, biases + 288,
        biases + 384, biases + 480, biases + 576, biases + 672,
        b2, flag, prog);
}